// Round 13
// baseline (2824.151 us; speedup 1.0000x reference)
//
#include <hip/hip_runtime.h>
#include <hip/hip_bf16.h>

#define B_ 128
#define T_ 512
#define I_ 64
#define H_ 1024
#define O_ 12
#define XSTEP (I_ * B_)   // 8192 bf16 elements per timestep of xPhi
#define RSLOT 16384       // shorts per ring slot: 128 kb * 16 batches * 8
#define TIMEOUT 2000      // fast-flag poll rounds before sticky fallback
#define OSTRIDE 193       // outS row stride (floats): co-prime with 32 banks

typedef __attribute__((ext_vector_type(8))) short bf16x8;
typedef __attribute__((ext_vector_type(4))) float f32x4;

#define MFMA16 __builtin_amdgcn_mfma_f32_16x16x32_bf16

__device__ __forceinline__ float bf2f(unsigned short s) {
  unsigned u = ((unsigned)s) << 16; float f; __builtin_memcpy(&f, &u, 4); return f;
}
__device__ __forceinline__ unsigned short f2bf(float f) {
  unsigned u; __builtin_memcpy(&u, &f, 4);
  u += 0x7fffu + ((u >> 16) & 1u);   // RNE (finite inputs only here)
  return (unsigned short)(u >> 16);
}

// ---- proven agent-scope (LLC) atomics (rounds 1-3) ----
__device__ __forceinline__ unsigned ldA32(const unsigned* p) {
  return __hip_atomic_load(p, __ATOMIC_RELAXED, __HIP_MEMORY_SCOPE_AGENT);
}
__device__ __forceinline__ void stA32(unsigned* p, unsigned v) {
  __hip_atomic_store(p, v, __ATOMIC_RELAXED, __HIP_MEMORY_SCOPE_AGENT);
}
__device__ __forceinline__ unsigned long long ldA64(const unsigned long long* p) {
  return __hip_atomic_load(p, __ATOMIC_RELAXED, __HIP_MEMORY_SCOPE_AGENT);
}

// ---- XCD-local primitives (sc0: bypass L1, served by this XCD's L2) ----
// Speed-only: every use has a proven-slow dual. Never load-bearing for
// correctness or termination.
__device__ __forceinline__ void store32_sc0(unsigned* p, unsigned v) {
  asm volatile("global_store_dword %0, %1, off sc0" :: "v"(p), "v"(v) : "memory");
}
__device__ __forceinline__ unsigned poll_sc0(const unsigned* p) {
  unsigned v;
  asm volatile("global_load_dword %0, %1, off sc0\n\ts_waitcnt vmcnt(0)"
               : "=v"(v) : "v"(p) : "memory");
  return v;
}
__device__ __forceinline__ bf16x8 load16_sc0(const void* p) {
  bf16x8 v;
  asm volatile("global_load_dwordx4 %0, %1, off sc0" : "=v"(v) : "v"(p));
  return v;
}
__device__ __forceinline__ void waitv8(bf16x8& v0, bf16x8& v1, bf16x8& v2, bf16x8& v3,
                                       bf16x8& v4, bf16x8& v5, bf16x8& v6, bf16x8& v7) {
  asm volatile("s_waitcnt vmcnt(0)"
               : "+v"(v0), "+v"(v1), "+v"(v2), "+v"(v3),
                 "+v"(v4), "+v"(v5), "+v"(v6), "+v"(v7) :: "memory");
}

// ---- merged prep (one launch): blocks 0..511 pack xPhi; blocks 512..575
// zero flags + init out with bias (the fused projection atomicAdds onto it).
// bar uints: [0..255] fast flags (sc0 medium), [256..511] slow flags (LLC).
__global__ void prep_all(const float* __restrict__ x,
                         unsigned short* __restrict__ xPhi,
                         const float* __restrict__ b_out,
                         float* __restrict__ out,
                         unsigned* __restrict__ bar) {
  if (blockIdx.x < T_) {
    // x[b][t][i] fp32 -> pack-layout bf16 plane xPhi[t][i/8][b][i%8]
    const int t = blockIdx.x;
    for (int u = threadIdx.x; u < 1024; u += 256) {   // u = ib*128 + b
      const int ib = u >> 7, b = u & 127;
      const float* src = x + ((size_t)b * T_ + t) * I_ + ib * 8;
      bf16x8 hi;
      #pragma unroll
      for (int j = 0; j < 8; ++j) hi[j] = (short)f2bf(src[j]);
      *(bf16x8*)(xPhi + ((size_t)t * 1024 + u) * 8) = hi;
    }
  } else {
    const int idx = (blockIdx.x - T_) * 256 + threadIdx.x;  // 64 blocks: 16384
    if (idx < 1024) bar[idx] = 0u;
    float bo[12];
    #pragma unroll
    for (int o = 0; o < 12; ++o) bo[o] = b_out[o];
    for (int r = idx; r < B_ * T_; r += 16384) {
      #pragma unroll
      for (int o = 0; o < 12; ++o) out[(size_t)r * 12 + o] = bo[o];
    }
  }
}

// ---- persistent MFMA recurrence + fused output projection ----
// r11 skeleton (r0 protocol + fused projection, best measured 1786-1790us)
// with ONE change: the rS (LLC insurance) stores are evicted from drain #1.
//  - epilogue publishes rF (sc0) only -> drain #1 waits L2 acks (~300cy),
//    not the ~600-700cy LLC ack. Fast flag posts ~600cy earlier per step.
//  - post-bar2, waves 1-3 issue ALL 256 rS stores (wave 1 covers wave 0's
//    share via pkS in LDS), run the out-reduce while acks fly, then a
//    wave-local vmcnt(0), then tid 64 posts the SLOW flag -> slow flag is
//    still ordered after all rS data (r0 invariant preserved). Waves 1-3
//    never block before posting => deadlock-free. Wave 0 (poller) issues
//    no LLC traffic => clean poll queue.
// r3/r7 tried this move but bundled it with cold-hP insurance lines and
// poller restructures; this is the isolated warm-ring variant.
__global__ __launch_bounds__(256, 1) void rnn_mfma(
    const float* __restrict__ W_ih, const float* __restrict__ W_hh,
    const float* __restrict__ b_ih, const float* __restrict__ b_hh,
    const float* __restrict__ W_out, const unsigned short* __restrict__ xPhi,
    unsigned short* __restrict__ rF, unsigned short* __restrict__ rS,
    unsigned* __restrict__ bar, float* __restrict__ out)
{
  __shared__ float part[4][544];        // 8 rows x 68 (padded: conflict-free)
  __shared__ float outS[16 * OSTRIDE];  // [rp][n*12+o] out partials (12.4 KB)
  __shared__ float biasS[32];
  __shared__ unsigned pkS[64];          // wave 0's packed h (wave 1 posts rS)
  __shared__ unsigned modeS;        // 1 = fast, one-way latch to 0
  const int tid = threadIdx.x, bid = blockIdx.x;
  const int wave = tid >> 6, lane = tid & 63, quad = lane >> 4, ln = lane & 15;
  const int g = bid & 7, rg = bid >> 3;
  const int r0 = rg * 32, b0 = g * 16;
  if (tid < 32) biasS[tid] = b_ih[r0 + tid] + b_hh[r0 + tid];
  if (tid == 0) modeS = 1u;

  // W_out rows for this thread's 2 output rows, preloaded once (24 VGPRs).
  float wo[12][2];
  {
    const int R = r0 + (tid >> 4) * 2;
    #pragma unroll
    for (int o = 0; o < 12; ++o) {
      wo[o][0] = W_out[(size_t)o * H_ + R];
      wo[o][1] = W_out[(size_t)o * H_ + R + 1];
    }
  }

  // A-frags for W_hh (hi/lo split -> fp32-grade W precision), loaded once.
  bf16x8 ahhi[2][8], ahlo[2][8];
  #pragma unroll
  for (int mt = 0; mt < 2; ++mt)
    #pragma unroll
    for (int kt = 0; kt < 8; ++kt) {
      const float* wp = W_hh + (size_t)(r0 + mt * 16 + ln) * H_
                        + wave * 256 + kt * 32 + quad * 8;
      #pragma unroll
      for (int j = 0; j < 8; ++j) {
        float v = wp[j];
        unsigned short h = f2bf(v);
        ahhi[mt][kt][j] = (short)h;
        ahlo[mt][kt][j] = (short)f2bf(v - bf2f(h));
      }
    }
  // A-frags for W_ih: waves 0,1 own the two x K-tiles (i in [32w,32w+32)).
  bf16x8 axhi[2], axlo[2];
  if (wave < 2)
    #pragma unroll
    for (int mt = 0; mt < 2; ++mt) {
      const float* wp = W_ih + (size_t)(r0 + mt * 16 + ln) * I_
                        + wave * 32 + quad * 8;
      #pragma unroll
      for (int j = 0; j < 8; ++j) {
        float v = wp[j];
        unsigned short h = f2bf(v);
        axhi[mt][j] = (short)h;
        axlo[mt][j] = (short)f2bf(v - bf2f(h));
      }
    }
  __syncthreads();
  unsigned mode = 1u;               // block-uniform; updated only at barriers

  const int bcol = b0 + ln;
  unsigned short* rFg = rF + (size_t)g * 2 * RSLOT;
  unsigned short* rSg = rS + (size_t)g * 2 * RSLOT;

  f32x4 xacc0 = {0.f, 0.f, 0.f, 0.f}, xacc1 = {0.f, 0.f, 0.f, 0.f};
  auto computeX = [&](int t) {      // x-contribution for step t (waves 0,1)
    if (wave < 2) {
      const size_t xo = (((size_t)t * 8 + wave * 4 + quad) * B_ + bcol) * 8;
      bf16x8 bxh = *(const bf16x8*)(xPhi + xo);
      f32x4 t0 = {0.f, 0.f, 0.f, 0.f}, t1 = {0.f, 0.f, 0.f, 0.f};
      t0 = MFMA16(axhi[0], bxh, t0, 0, 0, 0);
      t0 = MFMA16(axlo[0], bxh, t0, 0, 0, 0);
      t1 = MFMA16(axhi[1], bxh, t1, 0, 0, 0);
      t1 = MFMA16(axlo[1], bxh, t1, 0, 0, 0);
      xacc0 = t0; xacc1 = t1;
    }
  };
  computeX(0);

  // 192 idle-wave threads: reduce 16 row-partials, one atomicAdd each.
  // Read addr = rp2*OSTRIDE + j -> lane-consecutive, conflict-free.
  auto outReduce = [&](int t) {
    if (tid >= 64) {
      const int j = tid - 64;                 // 0..191
      const int n2 = j / 12, o = j - n2 * 12; // n2 0..15, o 0..11
      float acc = 0.f;
      #pragma unroll
      for (int rp2 = 0; rp2 < 16; ++rp2)
        acc += outS[rp2 * OSTRIDE + n2 * 12 + o];
      atomicAdd(&out[((size_t)(b0 + n2) * T_ + t) * 12 + o], acc);
    }
  };

  for (int t = 0; t < T_; ++t) {
    // split accumulators: hi-chain (A) and lo-chain (B) -> halved dep chains
    f32x4 accA0 = xacc0, accA1 = xacc1;
    f32x4 accB0 = {0.f, 0.f, 0.f, 0.f}, accB1 = {0.f, 0.f, 0.f, 0.f};

    if (t > 0) {
      const int soff = ((wave * 32 + quad) * 16 + ln) * 8;   // shorts
      bf16x8 bh[8];
      if (mode) {
        const unsigned short* slot = rFg + ((t - 1) & 1) * RSLOT + soff;
        #pragma unroll
        for (int kt = 0; kt < 8; ++kt)
          bh[kt] = load16_sc0(slot + kt * 512);              // XCD-L2 hits
        waitv8(bh[0], bh[1], bh[2], bh[3], bh[4], bh[5], bh[6], bh[7]);
      } else {
        const unsigned long long* slot =
            (const unsigned long long*)(rSg + ((t - 1) & 1) * RSLOT + soff);
        #pragma unroll
        for (int kt = 0; kt < 8; ++kt) {
          union { unsigned long long u[2]; bf16x8 v; } U;
          U.u[0] = ldA64(slot + kt * 128);
          U.u[1] = ldA64(slot + kt * 128 + 1);
          bh[kt] = U.v;
        }
      }
      #pragma unroll
      for (int kt = 0; kt < 8; ++kt) {
        accA0 = MFMA16(ahhi[0][kt], bh[kt], accA0, 0, 0, 0);
        accA1 = MFMA16(ahhi[1][kt], bh[kt], accA1, 0, 0, 0);
        accB0 = MFMA16(ahlo[0][kt], bh[kt], accB0, 0, 0, 0);
        accB1 = MFMA16(ahlo[1][kt], bh[kt], accB1, 0, 0, 0);
      }
    }

    // combine K-split partials across waves via LDS (rows padded to 68)
    #pragma unroll
    for (int r = 0; r < 4; ++r) {
      part[wave][r * 68 + lane]       = accA0[r] + accB0[r];
      part[wave][(4 + r) * 68 + lane] = accA1[r] + accB1[r];
    }
    __syncthreads();                                         // barrier #1

    // epilogue: 256 threads, 2 rows each; rF publish + out partials.
    // rS moves post-bar2 (waves 1-3) so drain #1 is sc0-only.
    unsigned pk; int soffp;
    {
      const int n = tid & 15, rp = tid >> 4;
      const int m0 = rp * 2;
      float hv[2];
      unsigned short o2[2];
      #pragma unroll
      for (int rr = 0; rr < 2; ++rr) {
        const int m = m0 + rr;
        const int f = ((m >> 4) * 4 + (m & 3)) * 68 + ((m >> 2) & 3) * 16 + n;
        float s = part[0][f] + part[1][f] + part[2][f] + part[3][f] + biasS[m];
        hv[rr] = tanhf(s);
        o2[rr] = f2bf(hv[rr]);
      }
      pk = (unsigned)o2[0] | ((unsigned)o2[1] << 16);
      const int R = r0 + m0;
      soffp = ((R >> 3) * 16 + n) * 8 + (R & 7);
      store32_sc0((unsigned*)(rFg + (t & 1) * RSLOT + soffp), pk);
      if (tid < 64) pkS[tid] = pk;   // wave 1 posts our rS share post-bar2
      // out partials: addr = rp*OSTRIDE + n*12 + o -> 2 lanes/bank (free)
      #pragma unroll
      for (int o = 0; o < 12; ++o)
        outS[rp * OSTRIDE + n * 12 + o] = wo[o][0] * hv[0] + wo[o][1] * hv[1];
    }

    if (t < T_ - 1) {
      computeX(t + 1);                                   // independent of h_t
      asm volatile("s_waitcnt vmcnt(0)" ::: "memory");   // sc0 acks only now
      __syncthreads();                                   // barrier #2
      if (tid == 0) store32_sc0(&bar[g * 32 + rg], (unsigned)(t + 1));
      if (tid >= 64) {
        // LLC insurance off the critical chain: own share + wave 1 covers
        // wave 0's (from pkS). Acks overlap the out-reduce below.
        stA32((unsigned*)(rSg + (t & 1) * RSLOT + soffp), pk);
        if (tid < 128) {
          const int p = tid - 64;
          const int pn = p & 15, pm0 = (p >> 4) * 2;
          const int PR = r0 + pm0;
          const int psoff = ((PR >> 3) * 16 + pn) * 8 + (PR & 7);
          stA32((unsigned*)(rSg + (t & 1) * RSLOT + psoff), pkS[p]);
        }
        outReduce(t);              // projection hidden in the poll window
        asm volatile("s_waitcnt vmcnt(0)" ::: "memory");  // all rS ack'd
        if (tid == 64)             // slow flag ordered AFTER all rS data
          stA32(&bar[256 + g * 32 + rg], (unsigned)(t + 1));
      } else {
        int ok = 0;
        if (mode) {                // clean-queue poller (no LLC traffic)
          for (int it = 0; it < TIMEOUT && !ok; ++it) {
            unsigned v = (lane < 32) ? poll_sc0(&bar[g * 32 + lane]) : 0xffffffffu;
            ok = __all((int)(v >= (unsigned)(t + 1)));
          }
        }
        if (!ok) {                 // sticky fallback to proven LLC protocol
          if (tid == 0) modeS = 0u;
          for (;;) {
            unsigned v = (lane < 32) ? ldA32(&bar[256 + g * 32 + lane]) : 0xffffffffu;
            if (__all((int)(v >= (unsigned)(t + 1)))) break;
            __builtin_amdgcn_s_sleep(1);
          }
        }
      }
      __syncthreads();                                   // barrier #3
      mode = modeS;                // block-uniform mode for next step's loads
    }
  }

  // final step's projection (no flag/poll section at t = T_-1)
  __syncthreads();
  outReduce(T_ - 1);
}

// ---- host ----
extern "C" void kernel_launch(void* const* d_in, const int* in_sizes, int n_in,
                              void* d_out, int out_size, void* d_ws, size_t ws_size,
                              hipStream_t stream)
{
  const float* x     = (const float*)d_in[0];
  const float* W_ih  = (const float*)d_in[1];
  const float* W_hh  = (const float*)d_in[2];
  const float* b_ih  = (const float*)d_in[3];
  const float* b_hh  = (const float*)d_in[4];
  const float* W_out = (const float*)d_in[5];
  const float* b_out = (const float*)d_in[6];
  float* out = (float*)d_out;

  unsigned short* xPhi = (unsigned short*)d_ws;                  // 8.4 MB
  unsigned short* rF   = xPhi + (size_t)T_ * XSTEP;              // 512 KB
  unsigned short* rS   = rF + (size_t)8 * 2 * RSLOT;             // 512 KB
  unsigned*       bar  = (unsigned*)(rS + (size_t)8 * 2 * RSLOT); // 4 KB

  prep_all <<<T_ + 64, 256, 0, stream>>>(x, xPhi, b_out, out, bar);
  rnn_mfma <<<256, 256, 0, stream>>>(W_ih, W_hh, b_ih, b_hh, W_out,
                                     xPhi, rF, rS, bar, out);
}

// Round 14
// 1781.999 us; speedup vs baseline: 1.5848x; 1.5848x over previous
//
#include <hip/hip_runtime.h>
#include <hip/hip_bf16.h>

#define B_ 128
#define T_ 512
#define I_ 64
#define H_ 1024
#define O_ 12
#define XSTEP (I_ * B_)   // 8192 bf16 elements per timestep of xPhi
#define RSLOT 16384       // shorts per ring slot: 128 kb * 16 batches * 8
#define TIMEOUT 2000      // fast-flag poll rounds before sticky fallback
#define OSTRIDE 193       // outS row stride (floats): co-prime with 32 banks

typedef __attribute__((ext_vector_type(8))) short bf16x8;
typedef __attribute__((ext_vector_type(4))) float f32x4;

#define MFMA16 __builtin_amdgcn_mfma_f32_16x16x32_bf16

__device__ __forceinline__ float bf2f(unsigned short s) {
  unsigned u = ((unsigned)s) << 16; float f; __builtin_memcpy(&f, &u, 4); return f;
}
__device__ __forceinline__ unsigned short f2bf(float f) {
  unsigned u; __builtin_memcpy(&u, &f, 4);
  u += 0x7fffu + ((u >> 16) & 1u);   // RNE (finite inputs only here)
  return (unsigned short)(u >> 16);
}

// ---- proven agent-scope (LLC) atomics (rounds 1-3) ----
__device__ __forceinline__ unsigned ldA32(const unsigned* p) {
  return __hip_atomic_load(p, __ATOMIC_RELAXED, __HIP_MEMORY_SCOPE_AGENT);
}
__device__ __forceinline__ void stA32(unsigned* p, unsigned v) {
  __hip_atomic_store(p, v, __ATOMIC_RELAXED, __HIP_MEMORY_SCOPE_AGENT);
}
__device__ __forceinline__ unsigned long long ldA64(const unsigned long long* p) {
  return __hip_atomic_load(p, __ATOMIC_RELAXED, __HIP_MEMORY_SCOPE_AGENT);
}

// ---- XCD-local primitives (sc0: bypass L1, served by this XCD's L2) ----
// Speed-only: every use has a proven-slow dual. Never load-bearing for
// correctness or termination.
__device__ __forceinline__ void store32_sc0(unsigned* p, unsigned v) {
  asm volatile("global_store_dword %0, %1, off sc0" :: "v"(p), "v"(v) : "memory");
}
__device__ __forceinline__ unsigned poll_sc0(const unsigned* p) {
  unsigned v;
  asm volatile("global_load_dword %0, %1, off sc0\n\ts_waitcnt vmcnt(0)"
               : "=v"(v) : "v"(p) : "memory");
  return v;
}
__device__ __forceinline__ bf16x8 load16_sc0(const void* p) {
  bf16x8 v;
  asm volatile("global_load_dwordx4 %0, %1, off sc0" : "=v"(v) : "v"(p));
  return v;
}
__device__ __forceinline__ void waitv8(bf16x8& v0, bf16x8& v1, bf16x8& v2, bf16x8& v3,
                                       bf16x8& v4, bf16x8& v5, bf16x8& v6, bf16x8& v7) {
  asm volatile("s_waitcnt vmcnt(0)"
               : "+v"(v0), "+v"(v1), "+v"(v2), "+v"(v3),
                 "+v"(v4), "+v"(v5), "+v"(v6), "+v"(v7) :: "memory");
}

// ---- merged prep (one launch): blocks 0..511 pack xPhi; blocks 512..575
// zero flags + init out with bias (the fused projection atomicAdds onto it).
// bar uints: [0..255] fast flags (sc0 medium), [256..511] slow flags (LLC).
__global__ void prep_all(const float* __restrict__ x,
                         unsigned short* __restrict__ xPhi,
                         const float* __restrict__ b_out,
                         float* __restrict__ out,
                         unsigned* __restrict__ bar) {
  if (blockIdx.x < T_) {
    // x[b][t][i] fp32 -> pack-layout bf16 plane xPhi[t][i/8][b][i%8]
    const int t = blockIdx.x;
    for (int u = threadIdx.x; u < 1024; u += 256) {   // u = ib*128 + b
      const int ib = u >> 7, b = u & 127;
      const float* src = x + ((size_t)b * T_ + t) * I_ + ib * 8;
      bf16x8 hi;
      #pragma unroll
      for (int j = 0; j < 8; ++j) hi[j] = (short)f2bf(src[j]);
      *(bf16x8*)(xPhi + ((size_t)t * 1024 + u) * 8) = hi;
    }
  } else {
    const int idx = (blockIdx.x - T_) * 256 + threadIdx.x;  // 64 blocks: 16384
    if (idx < 1024) bar[idx] = 0u;
    float bo[12];
    #pragma unroll
    for (int o = 0; o < 12; ++o) bo[o] = b_out[o];
    for (int r = idx; r < B_ * T_; r += 16384) {
      #pragma unroll
      for (int o = 0; o < 12; ++o) out[(size_t)r * 12 + o] = bo[o];
    }
  }
}

// ---- persistent MFMA recurrence + fused output projection ----
// FINAL (r11, best measured: 1786/1790us, steady dispatch ~1745-1760).
// Protocol byte-identical to round 0 — empirically the best of NINE probed
// variants (alternatives 2490-3400us: per-wave flag gating, flag-line
// padding, drain restructures x4, data-as-flag x2, per-wave dependency
// narrowing). Load-bearing structure (4x independently confirmed): single
// poller wave + block-wide modeS broadcast + ONE batched drain covering ALL
// publish traffic (sc0 + LLC acks overlap in one queue; any split pays two
// serialized drains) + post-drain flag post so consumers trust flags with
// single-pass loads. Fusion (r8, -95us verified): projection partials in
// the epilogue, reduced by idle waves inside the poll window; outS stride
// 193 = bank-conflict-free (r9: conflicts 121.6M -> 21.0M verified).
__global__ __launch_bounds__(256, 1) void rnn_mfma(
    const float* __restrict__ W_ih, const float* __restrict__ W_hh,
    const float* __restrict__ b_ih, const float* __restrict__ b_hh,
    const float* __restrict__ W_out, const unsigned short* __restrict__ xPhi,
    unsigned short* __restrict__ rF, unsigned short* __restrict__ rS,
    unsigned* __restrict__ bar, float* __restrict__ out)
{
  __shared__ float part[4][544];        // 8 rows x 68 (padded: conflict-free)
  __shared__ float outS[16 * OSTRIDE];  // [rp][n*12+o] out partials (12.4 KB)
  __shared__ float biasS[32];
  __shared__ unsigned modeS;        // 1 = fast, one-way latch to 0
  const int tid = threadIdx.x, bid = blockIdx.x;
  const int wave = tid >> 6, lane = tid & 63, quad = lane >> 4, ln = lane & 15;
  const int g = bid & 7, rg = bid >> 3;
  const int r0 = rg * 32, b0 = g * 16;
  if (tid < 32) biasS[tid] = b_ih[r0 + tid] + b_hh[r0 + tid];
  if (tid == 0) modeS = 1u;

  // W_out rows for this thread's 2 output rows, preloaded once (24 VGPRs).
  float wo[12][2];
  {
    const int R = r0 + (tid >> 4) * 2;
    #pragma unroll
    for (int o = 0; o < 12; ++o) {
      wo[o][0] = W_out[(size_t)o * H_ + R];
      wo[o][1] = W_out[(size_t)o * H_ + R + 1];
    }
  }

  // A-frags for W_hh (hi/lo split -> fp32-grade W precision), loaded once.
  bf16x8 ahhi[2][8], ahlo[2][8];
  #pragma unroll
  for (int mt = 0; mt < 2; ++mt)
    #pragma unroll
    for (int kt = 0; kt < 8; ++kt) {
      const float* wp = W_hh + (size_t)(r0 + mt * 16 + ln) * H_
                        + wave * 256 + kt * 32 + quad * 8;
      #pragma unroll
      for (int j = 0; j < 8; ++j) {
        float v = wp[j];
        unsigned short h = f2bf(v);
        ahhi[mt][kt][j] = (short)h;
        ahlo[mt][kt][j] = (short)f2bf(v - bf2f(h));
      }
    }
  // A-frags for W_ih: waves 0,1 own the two x K-tiles (i in [32w,32w+32)).
  bf16x8 axhi[2], axlo[2];
  if (wave < 2)
    #pragma unroll
    for (int mt = 0; mt < 2; ++mt) {
      const float* wp = W_ih + (size_t)(r0 + mt * 16 + ln) * I_
                        + wave * 32 + quad * 8;
      #pragma unroll
      for (int j = 0; j < 8; ++j) {
        float v = wp[j];
        unsigned short h = f2bf(v);
        axhi[mt][j] = (short)h;
        axlo[mt][j] = (short)f2bf(v - bf2f(h));
      }
    }
  __syncthreads();
  unsigned mode = 1u;               // block-uniform; updated only at barriers

  const int bcol = b0 + ln;
  unsigned short* rFg = rF + (size_t)g * 2 * RSLOT;
  unsigned short* rSg = rS + (size_t)g * 2 * RSLOT;

  f32x4 xacc0 = {0.f, 0.f, 0.f, 0.f}, xacc1 = {0.f, 0.f, 0.f, 0.f};
  auto computeX = [&](int t) {      // x-contribution for step t (waves 0,1)
    if (wave < 2) {
      const size_t xo = (((size_t)t * 8 + wave * 4 + quad) * B_ + bcol) * 8;
      bf16x8 bxh = *(const bf16x8*)(xPhi + xo);
      f32x4 t0 = {0.f, 0.f, 0.f, 0.f}, t1 = {0.f, 0.f, 0.f, 0.f};
      t0 = MFMA16(axhi[0], bxh, t0, 0, 0, 0);
      t0 = MFMA16(axlo[0], bxh, t0, 0, 0, 0);
      t1 = MFMA16(axhi[1], bxh, t1, 0, 0, 0);
      t1 = MFMA16(axlo[1], bxh, t1, 0, 0, 0);
      xacc0 = t0; xacc1 = t1;
    }
  };
  computeX(0);

  // 192 idle-wave threads: reduce 16 row-partials, one atomicAdd each.
  // Read addr = rp2*OSTRIDE + j -> lane-consecutive, conflict-free.
  auto outReduce = [&](int t) {
    if (tid >= 64) {
      const int j = tid - 64;                 // 0..191
      const int n2 = j / 12, o = j - n2 * 12; // n2 0..15, o 0..11
      float acc = 0.f;
      #pragma unroll
      for (int rp2 = 0; rp2 < 16; ++rp2)
        acc += outS[rp2 * OSTRIDE + n2 * 12 + o];
      atomicAdd(&out[((size_t)(b0 + n2) * T_ + t) * 12 + o], acc);
    }
  };

  for (int t = 0; t < T_; ++t) {
    // split accumulators: hi-chain (A) and lo-chain (B) -> halved dep chains
    f32x4 accA0 = xacc0, accA1 = xacc1;
    f32x4 accB0 = {0.f, 0.f, 0.f, 0.f}, accB1 = {0.f, 0.f, 0.f, 0.f};

    if (t > 0) {
      const int soff = ((wave * 32 + quad) * 16 + ln) * 8;   // shorts
      bf16x8 bh[8];
      if (mode) {
        const unsigned short* slot = rFg + ((t - 1) & 1) * RSLOT + soff;
        #pragma unroll
        for (int kt = 0; kt < 8; ++kt)
          bh[kt] = load16_sc0(slot + kt * 512);              // XCD-L2 hits
        waitv8(bh[0], bh[1], bh[2], bh[3], bh[4], bh[5], bh[6], bh[7]);
      } else {
        const unsigned long long* slot =
            (const unsigned long long*)(rSg + ((t - 1) & 1) * RSLOT + soff);
        #pragma unroll
        for (int kt = 0; kt < 8; ++kt) {
          union { unsigned long long u[2]; bf16x8 v; } U;
          U.u[0] = ldA64(slot + kt * 128);
          U.u[1] = ldA64(slot + kt * 128 + 1);
          bh[kt] = U.v;
        }
      }
      #pragma unroll
      for (int kt = 0; kt < 8; ++kt) {
        accA0 = MFMA16(ahhi[0][kt], bh[kt], accA0, 0, 0, 0);
        accA1 = MFMA16(ahhi[1][kt], bh[kt], accA1, 0, 0, 0);
        accB0 = MFMA16(ahlo[0][kt], bh[kt], accB0, 0, 0, 0);
        accB1 = MFMA16(ahlo[1][kt], bh[kt], accB1, 0, 0, 0);
      }
    }

    // combine K-split partials across waves via LDS (rows padded to 68)
    #pragma unroll
    for (int r = 0; r < 4; ++r) {
      part[wave][r * 68 + lane]       = accA0[r] + accB0[r];
      part[wave][(4 + r) * 68 + lane] = accA1[r] + accB1[r];
    }
    __syncthreads();

    // epilogue: 256 threads, 2 rows each; dual-publish rings + out partials
    {
      const int n = tid & 15, rp = tid >> 4;
      const int m0 = rp * 2;
      float hv[2];
      unsigned short o2[2];
      #pragma unroll
      for (int rr = 0; rr < 2; ++rr) {
        const int m = m0 + rr;
        const int f = ((m >> 4) * 4 + (m & 3)) * 68 + ((m >> 2) & 3) * 16 + n;
        float s = part[0][f] + part[1][f] + part[2][f] + part[3][f] + biasS[m];
        hv[rr] = tanhf(s);
        o2[rr] = f2bf(hv[rr]);
      }
      const unsigned pk = (unsigned)o2[0] | ((unsigned)o2[1] << 16);
      const int R = r0 + m0;
      // rings first (group-local batch index n); acks overlap the FMAs below
      const int soff = ((R >> 3) * 16 + n) * 8 + (R & 7);
      store32_sc0((unsigned*)(rFg + (t & 1) * RSLOT + soff), pk);
      stA32      ((unsigned*)(rSg + (t & 1) * RSLOT + soff), pk);
      // out partials: addr = rp*OSTRIDE + n*12 + o -> 2 lanes/bank (free)
      #pragma unroll
      for (int o = 0; o < 12; ++o)
        outS[rp * OSTRIDE + n * 12 + o] = wo[o][0] * hv[0] + wo[o][1] * hv[1];
    }

    if (t < T_ - 1) {
      computeX(t + 1);                                   // independent of h_t
      asm volatile("s_waitcnt vmcnt(0)" ::: "memory");   // all publishes ack'd
      __syncthreads();                                   // also guards part/outS
      if (tid == 0) {
        store32_sc0(&bar[g * 32 + rg],      (unsigned)(t + 1));   // fast flag
        stA32      (&bar[256 + g * 32 + rg], (unsigned)(t + 1));  // slow flag
      }
      if (tid < 64) {
        int ok = 0;
        if (mode) {
          for (int it = 0; it < TIMEOUT && !ok; ++it) {
            unsigned v = (lane < 32) ? poll_sc0(&bar[g * 32 + lane]) : 0xffffffffu;
            ok = __all((int)(v >= (unsigned)(t + 1)));
          }
        }
        if (!ok) {                 // sticky fallback to proven LLC protocol
          if (tid == 0) modeS = 0u;
          for (;;) {
            unsigned v = (lane < 32) ? ldA32(&bar[256 + g * 32 + lane]) : 0xffffffffu;
            if (__all((int)(v >= (unsigned)(t + 1)))) break;
            __builtin_amdgcn_s_sleep(1);
          }
        }
      } else {
        outReduce(t);              // idle waves: hide projection in poll window
      }
      __syncthreads();
      mode = modeS;                // block-uniform mode for next step's loads
    }
  }

  // final step's projection (no flag/poll section at t = T_-1)
  __syncthreads();
  outReduce(T_ - 1);
}

// ---- host ----
extern "C" void kernel_launch(void* const* d_in, const int* in_sizes, int n_in,
                              void* d_out, int out_size, void* d_ws, size_t ws_size,
                              hipStream_t stream)
{
  const float* x     = (const float*)d_in[0];
  const float* W_ih  = (const float*)d_in[1];
  const float* W_hh  = (const float*)d_in[2];
  const float* b_ih  = (const float*)d_in[3];
  const float* b_hh  = (const float*)d_in[4];
  const float* W_out = (const float*)d_in[5];
  const float* b_out = (const float*)d_in[6];
  float* out = (float*)d_out;

  unsigned short* xPhi = (unsigned short*)d_ws;                  // 8.4 MB
  unsigned short* rF   = xPhi + (size_t)T_ * XSTEP;              // 512 KB
  unsigned short* rS   = rF + (size_t)8 * 2 * RSLOT;             // 512 KB
  unsigned*       bar  = (unsigned*)(rS + (size_t)8 * 2 * RSLOT); // 4 KB

  prep_all <<<T_ + 64, 256, 0, stream>>>(x, xPhi, b_out, out, bar);
  rnn_mfma <<<256, 256, 0, stream>>>(W_ih, W_hh, b_ih, b_hh, W_out,
                                     xPhi, rF, rS, bar, out);
}